// Round 1
// baseline (2182.947 us; speedup 1.0000x reference)
//
#include <hip/hip_runtime.h>
#include <stdint.h>

// Problem constants
#define BDIM 8192
#define PDIM 4096
#define DDIM 1024
#define LDIM 5
#define KSEL 5
#define EPSV 1e-8f

// GEMM tile config
#define BM 64
#define BN 256
#define BK 16
#define SPLITS 8
#define CPS (PDIM / SPLITS)   // 512 cols per block
#define NTILES (CPS / BN)     // 2 col-tiles per block

// Candidate packing: (float_bits(dist) << 32) | key_index.
// dist is strictly positive here (cos | | << 1), so unsigned compare of the
// packed u64 == lexicographic (dist asc, idx asc) — exactly lax.top_k order
// (largest -dist first, ties -> lower index).
__device__ __forceinline__ void insert5(unsigned long long t[5], unsigned long long c) {
    if (c < t[4]) {
        if (c < t[3]) { t[4] = t[3];
            if (c < t[2]) { t[3] = t[2];
                if (c < t[1]) { t[2] = t[1];
                    if (c < t[0]) { t[1] = t[0]; t[0] = c; }
                    else t[1] = c;
                } else t[2] = c;
            } else t[3] = c;
        } else t[4] = c;
    }
}

// Kernel 1: row L2 norms of keys (blocks 0..P-1) and x (blocks P..P+B-1).
__global__ __launch_bounds__(256) void norms_kernel(
        const float* __restrict__ x, const float* __restrict__ keys,
        float* __restrict__ xn, float* __restrict__ kn) {
    int b = blockIdx.x;
    const float* src; float* dst;
    if (b < PDIM) { src = keys + (size_t)b * DDIM; dst = kn + b; }
    else          { src = x + (size_t)(b - PDIM) * DDIM; dst = xn + (b - PDIM); }
    float4 v = ((const float4*)src)[threadIdx.x];   // 256 threads * 4 = 1024
    float s = v.x*v.x + v.y*v.y + v.z*v.z + v.w*v.w;
    #pragma unroll
    for (int m = 32; m; m >>= 1) s += __shfl_xor(s, m, 64);
    __shared__ float red[4];
    if ((threadIdx.x & 63) == 0) red[threadIdx.x >> 6] = s;
    __syncthreads();
    if (threadIdx.x == 0) *dst = sqrtf(red[0] + red[1] + red[2] + red[3]);
}

// Kernel 2: fp32 GEMM tile (BM x BN, K=1024) with fused per-row top-5.
// Grid: (B/BM, SPLITS). Each block covers rows [bx*64, +64) x cols [by*512, +512).
// Thread layout: tx = tid&31 -> 8 cols, ty = tid>>5 -> 8 rows (8x8 acc).
__global__ __launch_bounds__(256) void score_topk_kernel(
        const float* __restrict__ x, const float* __restrict__ keys,
        const float* __restrict__ xn, const float* __restrict__ kn,
        unsigned long long* __restrict__ part) {
    __shared__ float Xs[BK][BM + 4];    // +4 pad, row stride 272 B (16B aligned)
    __shared__ float Ks[BK][BN + 8];    // +8 pad, row stride 1056 B (16B aligned)

    const int tid = threadIdx.x;
    const int tx = tid & 31, ty = tid >> 5;
    const int row0 = blockIdx.x * BM;
    const int split = blockIdx.y;
    const int rb = ty * 8, cb = tx * 8;

    unsigned long long t5[8][5];
    #pragma unroll
    for (int i = 0; i < 8; ++i)
        #pragma unroll
        for (int k = 0; k < 5; ++k) t5[i][k] = ~0ULL;

    for (int tile = 0; tile < NTILES; ++tile) {
        const int c0 = split * CPS + tile * BN;
        float acc[8][8];
        #pragma unroll
        for (int i = 0; i < 8; ++i)
            #pragma unroll
            for (int j = 0; j < 8; ++j) acc[i][j] = 0.f;

        for (int kc = 0; kc < DDIM; kc += BK) {
            // stage loads into registers first
            const int xr = tid >> 2, xk = (tid & 3) << 2;          // 64 rows x 16 k
            float4 xv = *(const float4*)&x[(size_t)(row0 + xr) * DDIM + kc + xk];
            float4 kv[4];
            #pragma unroll
            for (int i2 = 0; i2 < 4; ++i2) {
                int idx = tid + i2 * 256;                          // 256 rows x 16 k
                int kr = idx >> 2, kk = (idx & 3) << 2;
                kv[i2] = *(const float4*)&keys[(size_t)(c0 + kr) * DDIM + kc + kk];
            }
            __syncthreads();   // previous iteration's LDS reads done
            Xs[xk + 0][xr] = xv.x; Xs[xk + 1][xr] = xv.y;
            Xs[xk + 2][xr] = xv.z; Xs[xk + 3][xr] = xv.w;
            #pragma unroll
            for (int i2 = 0; i2 < 4; ++i2) {
                int idx = tid + i2 * 256;
                int kr = idx >> 2, kk = (idx & 3) << 2;
                Ks[kk + 0][kr] = kv[i2].x; Ks[kk + 1][kr] = kv[i2].y;
                Ks[kk + 2][kr] = kv[i2].z; Ks[kk + 3][kr] = kv[i2].w;
            }
            __syncthreads();

            #pragma unroll
            for (int k = 0; k < BK; ++k) {
                float a[8], bq[8];
                *(float4*)&a[0]  = *(const float4*)&Xs[k][rb];
                *(float4*)&a[4]  = *(const float4*)&Xs[k][rb + 4];
                *(float4*)&bq[0] = *(const float4*)&Ks[k][cb];
                *(float4*)&bq[4] = *(const float4*)&Ks[k][cb + 4];
                #pragma unroll
                for (int i = 0; i < 8; ++i)
                    #pragma unroll
                    for (int j = 0; j < 8; ++j)
                        acc[i][j] = fmaf(a[i], bq[j], acc[i][j]);
            }
        }

        // Epilogue: cos -> dist -> packed candidates into running top-5
        float kn8[8], xn8[8];
        #pragma unroll
        for (int j = 0; j < 8; ++j) kn8[j] = kn[c0 + cb + j];
        #pragma unroll
        for (int i = 0; i < 8; ++i) xn8[i] = xn[row0 + rb + i];
        #pragma unroll
        for (int i = 0; i < 8; ++i) {
            #pragma unroll
            for (int j = 0; j < 8; ++j) {
                float denom = fmaxf(xn8[i] * kn8[j], EPSV);
                float dist = 1.0f - acc[i][j] / denom;
                unsigned long long c =
                    ((unsigned long long)__float_as_uint(dist) << 32) |
                    (unsigned long long)(unsigned)(c0 + cb + j);
                insert5(t5[i], c);
            }
        }
    }

    // Butterfly merge across the 32 lanes (same ty) sharing each row.
    #pragma unroll
    for (int m = 1; m <= 16; m <<= 1) {
        #pragma unroll
        for (int i = 0; i < 8; ++i) {
            unsigned long long o[5];
            #pragma unroll
            for (int k = 0; k < 5; ++k) o[k] = __shfl_xor(t5[i][k], m, 64);
            #pragma unroll
            for (int k = 0; k < 5; ++k) insert5(t5[i], o[k]);
        }
    }
    if (tx == 0) {
        #pragma unroll
        for (int i = 0; i < 8; ++i) {
            size_t base = ((size_t)(row0 + rb + i) * SPLITS + split) * 5;
            #pragma unroll
            for (int k = 0; k < 5; ++k) part[base + k] = t5[i][k];
        }
    }
}

// Kernel 3: final per-row merge of 8 split-partials, gather values rows, row loss.
__global__ __launch_bounds__(256) void gather_kernel(
        const unsigned long long* __restrict__ part,
        const float* __restrict__ values,
        float* __restrict__ out, float* __restrict__ row_loss) {
    const int row = blockIdx.x;
    __shared__ int sidx[KSEL];
    if (threadIdx.x == 0) {
        unsigned long long t[5] = {~0ULL, ~0ULL, ~0ULL, ~0ULL, ~0ULL};
        const unsigned long long* p = part + (size_t)row * SPLITS * 5;
        #pragma unroll
        for (int i = 0; i < SPLITS * 5; ++i) insert5(t, p[i]);
        float s = 0.f;
        #pragma unroll
        for (int k = 0; k < KSEL; ++k) {
            sidx[k] = (int)(t[k] & 0xFFFFFFFFULL);
            s += __uint_as_float((unsigned)(t[k] >> 32));
        }
        row_loss[row] = s;
    }
    __syncthreads();
    float4* dst = (float4*)(out + (size_t)row * (KSEL * LDIM * DDIM));
    #pragma unroll
    for (int k = 0; k < KSEL; ++k) {
        const float4* src = (const float4*)(values + (size_t)sidx[k] * (LDIM * DDIM));
        float4* dstk = dst + k * (LDIM * DDIM / 4);
        for (int o = threadIdx.x; o < LDIM * DDIM / 4; o += 256) dstk[o] = src[o];
    }
}

// Kernel 4: deterministic loss reduction -> out[B*K*L*D]
__global__ __launch_bounds__(256) void loss_reduce_kernel(
        const float* __restrict__ row_loss, float* __restrict__ out_loss) {
    float s = 0.f;
    for (int i = threadIdx.x; i < BDIM; i += 256) s += row_loss[i];
    #pragma unroll
    for (int m = 32; m; m >>= 1) s += __shfl_xor(s, m, 64);
    __shared__ float red[4];
    if ((threadIdx.x & 63) == 0) red[threadIdx.x >> 6] = s;
    __syncthreads();
    if (threadIdx.x == 0)
        *out_loss = (red[0] + red[1] + red[2] + red[3]) * (1.0f / (BDIM * KSEL));
}

extern "C" void kernel_launch(void* const* d_in, const int* in_sizes, int n_in,
                              void* d_out, int out_size, void* d_ws, size_t ws_size,
                              hipStream_t stream) {
    const float* x      = (const float*)d_in[0];   // (B,1,D)
    const float* keys   = (const float*)d_in[1];   // (P,D)
    const float* values = (const float*)d_in[2];   // (P,L,D)
    float* out = (float*)d_out;                    // prompts (B*K*L*D) then loss (1)

    // Workspace layout (~2.7 MB)
    unsigned long long* part = (unsigned long long*)d_ws;            // B*SPLITS*5 u64 = 2,621,440 B
    float* kn       = (float*)((char*)d_ws + 2621440);               // P floats
    float* xn       = (float*)((char*)d_ws + 2621440 + 16384);       // B floats
    float* row_loss = (float*)((char*)d_ws + 2621440 + 16384 + 32768); // B floats

    norms_kernel<<<PDIM + BDIM, 256, 0, stream>>>(x, keys, xn, kn);
    score_topk_kernel<<<dim3(BDIM / BM, SPLITS), 256, 0, stream>>>(x, keys, xn, kn, part);
    gather_kernel<<<BDIM, 256, 0, stream>>>(part, values, out, row_loss);
    loss_reduce_kernel<<<1, 256, 0, stream>>>(row_loss, out + (size_t)BDIM * KSEL * LDIM * DDIM);
}